// Round 1
// baseline (381.134 us; speedup 1.0000x reference)
//
#include <hip/hip_runtime.h>
#include <math.h>

#define D_MODEL 2048
#define NE 64
#define NTOK 16384            // 4 * 4096 tokens
#define TW 16                 // tokens per block
#define KSPLIT 4              // waves per block; each wave does D_MODEL/KSPLIT
#define KW (D_MODEL / KSPLIT) // 512 K per wave
#define KC 32                 // K-chunk held in registers
#define NBLK (NTOK / TW)      // 1024 blocks

// Lane e <-> expert e. Each wave computes partial logits for 16 tokens over
// its 512-wide K-slice; W chunk lives in VGPRs (reused across 16 tokens),
// x is wave-uniform -> scalar/broadcast loads. Partials combined in LDS,
// then butterfly top-2 across the 64 lanes.
__global__ __launch_bounds__(256, 4)
void router_kernel(const float* __restrict__ x, const float* __restrict__ W,
                   const float* __restrict__ bias, float* __restrict__ out) {
  const int lane = threadIdx.x & 63;
  const int wv = __builtin_amdgcn_readfirstlane((int)(threadIdx.x >> 6));
  const int token0 = blockIdx.x * TW;

  __shared__ float part[KSPLIT][TW][NE]; // 16 KB

  float acc[TW];
#pragma unroll
  for (int t = 0; t < TW; ++t) acc[t] = 0.f;

  const float* wp = W + lane * D_MODEL + wv * KW; // per-lane expert row slice
  const float* xb = x + token0 * D_MODEL + wv * KW; // wave-uniform

  for (int kc = 0; kc < KW; kc += KC) {
    float4 wr[KC / 4];
#pragma unroll
    for (int j = 0; j < KC / 4; ++j)
      wr[j] = *(const float4*)(wp + kc + 4 * j);
#pragma unroll
    for (int t = 0; t < TW; ++t) {
      const float* xp = xb + t * D_MODEL + kc;
#pragma unroll
      for (int j = 0; j < KC / 4; ++j) {
        float4 xv = *(const float4*)(xp + 4 * j);
        acc[t] = fmaf(xv.x, wr[j].x, acc[t]);
        acc[t] = fmaf(xv.y, wr[j].y, acc[t]);
        acc[t] = fmaf(xv.z, wr[j].z, acc[t]);
        acc[t] = fmaf(xv.w, wr[j].w, acc[t]);
      }
    }
  }

#pragma unroll
  for (int t = 0; t < TW; ++t) part[wv][t][lane] = acc[t];
  __syncthreads();

  const float bl = bias[lane];
  const int tpw = TW / KSPLIT; // 4 epilogue tokens per wave
#pragma unroll
  for (int ti = 0; ti < tpw; ++ti) {
    const int t = wv * tpw + ti;
    float v1 = part[0][t][lane] + part[1][t][lane] + part[2][t][lane] +
               part[3][t][lane] + bl;
    int i1 = lane;
    float v2 = -INFINITY;
    int i2 = NE;
    // butterfly: each lane maintains top-2 (value desc, index asc on ties)
#pragma unroll
    for (int off = 32; off > 0; off >>= 1) {
      float ov1 = __shfl_xor(v1, off, 64);
      int   oi1 = __shfl_xor(i1, off, 64);
      float ov2 = __shfl_xor(v2, off, 64);
      int   oi2 = __shfl_xor(i2, off, 64);
      bool afirst = (v1 > ov1) || (v1 == ov1 && i1 < oi1);
      float w1v = afirst ? v1 : ov1;  int w1i = afirst ? i1 : oi1;
      float c1v = afirst ? v2 : ov2;  int c1i = afirst ? i2 : oi2; // winner's 2nd
      float c2v = afirst ? ov1 : v1;  int c2i = afirst ? oi1 : i1; // loser's 1st
      bool sfirst = (c1v > c2v) || (c1v == c2v && c1i < c2i);
      v1 = w1v; i1 = w1i;
      v2 = sfirst ? c1v : c2v;
      i2 = sfirst ? c1i : c2i;
    }
    if (lane == 0) {
      // normalized top-2 softmax weights: denominator cancels
      const float ex = expf(v2 - v1); // <= 1, no overflow
      const float den = 1.f + ex;
      const float n1 = 1.f / den;
      const float n2 = ex / den;
      const int token = token0 + t;
      *(float2*)(out + 2 * token) = make_float2(n1, n2);
      *(float2*)(out + 2 * NTOK + 2 * token) =
          make_float2((float)i1, (float)i2);
    }
  }
}

extern "C" void kernel_launch(void* const* d_in, const int* in_sizes, int n_in,
                              void* d_out, int out_size, void* d_ws, size_t ws_size,
                              hipStream_t stream) {
  const float* x = (const float*)d_in[0];
  const float* W = (const float*)d_in[1];
  const float* b = (const float*)d_in[2];
  float* out = (float*)d_out;
  hipLaunchKernelGGL(router_kernel, dim3(NBLK), dim3(256), 0, stream,
                     x, W, b, out);
}

// Round 2
// 231.796 us; speedup vs baseline: 1.6443x; 1.6443x over previous
//
#include <hip/hip_runtime.h>
#include <math.h>

#define DM 2048
#define NEXP 64
#define NTOK 16384
#define BT 32                 // tokens per block
#define NW 8                  // waves per block
#define KSL (DM / NW)         // 256-wide K slice per wave
#define NKS (KSL / 32)        // 8 k-steps of 32
#define NBLK (NTOK / BT)      // 512 blocks
#define WELEMS (NEXP * DM)    // 131072

typedef __attribute__((ext_vector_type(8))) short short8;
typedef __attribute__((ext_vector_type(4))) float f32x4;

// Split fp32 into three bf16 limbs (RNE at each level); hi+mid+lo is exact to
// ~2^-25 relative. All inputs are normal-range randoms (no inf/nan/subnormal).
__device__ __forceinline__ void split3(float f, unsigned short& h,
                                       unsigned short& m, unsigned short& l) {
  unsigned u = __float_as_uint(f);
  unsigned rh = (u + 0x7FFFu + ((u >> 16) & 1u)) >> 16;
  h = (unsigned short)rh;
  float f1 = f - __uint_as_float(rh << 16);
  unsigned u1 = __float_as_uint(f1);
  unsigned rm = (u1 + 0x7FFFu + ((u1 >> 16) & 1u)) >> 16;
  m = (unsigned short)rm;
  float f2 = f1 - __uint_as_float(rm << 16);
  unsigned u2 = __float_as_uint(f2);
  l = (unsigned short)((u2 + 0x7FFFu + ((u2 >> 16) & 1u)) >> 16);
}

// Pre-kernel: split W [64][2048] fp32 into 3 bf16 limb arrays in workspace.
__global__ void convw_kernel(const float* __restrict__ W,
                             unsigned short* __restrict__ whi,
                             unsigned short* __restrict__ wmid,
                             unsigned short* __restrict__ wlo) {
  int i = blockIdx.x * 256 + threadIdx.x;
  unsigned short h, m, l;
  split3(W[i], h, m, l);
  whi[i] = h; wmid[i] = m; wlo[i] = l;
}

// Main: MFMA bf16x3 GEMM [16384 x 2048] x [2048 x 64] + fused top-2 softmax.
// Wave layout: 16x16x32 MFMA; A frag = x[tok0+ms*16+col][k+quad*8 .. +7],
// B frag = W[nt*16+col][k+quad*8 .. +7]; C/D: row=quad*4+reg, col=lane&15.
template <bool USE_WS>
__global__ __launch_bounds__(512, 2)
void router_mfma(const float* __restrict__ x, const float* __restrict__ W,
                 const float* __restrict__ bias,
                 const unsigned short* __restrict__ whi,
                 const unsigned short* __restrict__ wmid,
                 const unsigned short* __restrict__ wlo,
                 float* __restrict__ out) {
  const int lane = threadIdx.x & 63;
  const int wv = threadIdx.x >> 6;
  const int col = lane & 15;
  const int quad = lane >> 4;
  const int tok0 = blockIdx.x * BT;
  const int k0 = wv * KSL;

  __shared__ float part[NW][BT][NEXP]; // 64 KB

  f32x4 acc[2][4];
#pragma unroll
  for (int ms = 0; ms < 2; ++ms)
#pragma unroll
    for (int nt = 0; nt < 4; ++nt) acc[ms][nt] = (f32x4){0.f, 0.f, 0.f, 0.f};

  for (int ks = 0; ks < NKS; ++ks) {
    const int k = k0 + ks * 32 + quad * 8;

    // ---- A fragments: load 8 fp32 per Mset, split into 3 bf16 limbs ----
    short8 ah[2], am[2], al[2];
#pragma unroll
    for (int ms = 0; ms < 2; ++ms) {
      const f32x4* ap = (const f32x4*)(x + (size_t)(tok0 + ms * 16 + col) * DM + k);
      f32x4 a0 = ap[0], a1 = ap[1];
      float av[8] = {a0.x, a0.y, a0.z, a0.w, a1.x, a1.y, a1.z, a1.w};
#pragma unroll
      for (int j = 0; j < 8; ++j) {
        unsigned short h, m, l;
        split3(av[j], h, m, l);
        ah[ms][j] = (short)h; am[ms][j] = (short)m; al[ms][j] = (short)l;
      }
    }

    // ---- B fragments per N-tile, then 6-product MFMA accumulate ----
#pragma unroll
    for (int nt = 0; nt < 4; ++nt) {
      short8 bh, bm, bl;
      const size_t widx = (size_t)(nt * 16 + col) * DM + k;
      if (USE_WS) {
        bh = *(const short8*)(whi + widx);
        bm = *(const short8*)(wmid + widx);
        bl = *(const short8*)(wlo + widx);
      } else {
        const f32x4* wp = (const f32x4*)(W + widx);
        f32x4 w0 = wp[0], w1 = wp[1];
        float wvv[8] = {w0.x, w0.y, w0.z, w0.w, w1.x, w1.y, w1.z, w1.w};
#pragma unroll
        for (int j = 0; j < 8; ++j) {
          unsigned short h, m, l;
          split3(wvv[j], h, m, l);
          bh[j] = (short)h; bm[j] = (short)m; bl[j] = (short)l;
        }
      }
#pragma unroll
      for (int ms = 0; ms < 2; ++ms) {
        f32x4 c = acc[ms][nt];
        c = __builtin_amdgcn_mfma_f32_16x16x32_bf16(ah[ms], bh, c, 0, 0, 0);
        c = __builtin_amdgcn_mfma_f32_16x16x32_bf16(ah[ms], bm, c, 0, 0, 0);
        c = __builtin_amdgcn_mfma_f32_16x16x32_bf16(am[ms], bh, c, 0, 0, 0);
        c = __builtin_amdgcn_mfma_f32_16x16x32_bf16(ah[ms], bl, c, 0, 0, 0);
        c = __builtin_amdgcn_mfma_f32_16x16x32_bf16(al[ms], bh, c, 0, 0, 0);
        c = __builtin_amdgcn_mfma_f32_16x16x32_bf16(am[ms], bm, c, 0, 0, 0);
        acc[ms][nt] = c;
      }
    }
  }

  // ---- dump partial logits to LDS: C/D row=quad*4+r, col=lane&15 ----
#pragma unroll
  for (int ms = 0; ms < 2; ++ms)
#pragma unroll
    for (int nt = 0; nt < 4; ++nt)
#pragma unroll
      for (int r = 0; r < 4; ++r)
        part[wv][ms * 16 + quad * 4 + r][nt * 16 + col] = acc[ms][nt][r];
  __syncthreads();

  // ---- reduce K-partials + bias, butterfly top-2 (verified round-1 code) ----
  const float bl_ = bias[lane];
#pragma unroll
  for (int ti = 0; ti < 4; ++ti) {
    const int t = wv * 4 + ti;
    float v1 = bl_;
#pragma unroll
    for (int p = 0; p < NW; ++p) v1 += part[p][t][lane];
    int i1 = lane;
    float v2 = -INFINITY;
    int i2 = NEXP;
#pragma unroll
    for (int off = 32; off > 0; off >>= 1) {
      float ov1 = __shfl_xor(v1, off, 64);
      int   oi1 = __shfl_xor(i1, off, 64);
      float ov2 = __shfl_xor(v2, off, 64);
      int   oi2 = __shfl_xor(i2, off, 64);
      bool afirst = (v1 > ov1) || (v1 == ov1 && i1 < oi1);
      float w1v = afirst ? v1 : ov1;  int w1i = afirst ? i1 : oi1;
      float c1v = afirst ? v2 : ov2;  int c1i = afirst ? i2 : oi2;
      float c2v = afirst ? ov1 : v1;  int c2i = afirst ? oi1 : i1;
      bool sfirst = (c1v > c2v) || (c1v == c2v && c1i < c2i);
      v1 = w1v; i1 = w1i;
      v2 = sfirst ? c1v : c2v;
      i2 = sfirst ? c1i : c2i;
    }
    if (lane == 0) {
      const float ex = expf(v2 - v1);
      const float den = 1.f + ex;
      const int token = tok0 + t;
      *(float2*)(out + 2 * token) = make_float2(1.f / den, ex / den);
      *(float2*)(out + 2 * NTOK + 2 * token) =
          make_float2((float)i1, (float)i2);
    }
  }
}

extern "C" void kernel_launch(void* const* d_in, const int* in_sizes, int n_in,
                              void* d_out, int out_size, void* d_ws, size_t ws_size,
                              hipStream_t stream) {
  const float* x = (const float*)d_in[0];
  const float* W = (const float*)d_in[1];
  const float* b = (const float*)d_in[2];
  float* out = (float*)d_out;

  const size_t need = 3ull * WELEMS * sizeof(unsigned short); // 768 KB
  if (ws_size >= need) {
    unsigned short* whi = (unsigned short*)d_ws;
    unsigned short* wmid = whi + WELEMS;
    unsigned short* wlo = wmid + WELEMS;
    hipLaunchKernelGGL(convw_kernel, dim3(WELEMS / 256), dim3(256), 0, stream,
                       W, whi, wmid, wlo);
    hipLaunchKernelGGL((router_mfma<true>), dim3(NBLK), dim3(512), 0, stream,
                       x, W, b, whi, wmid, wlo, out);
  } else {
    hipLaunchKernelGGL((router_mfma<false>), dim3(NBLK), dim3(512), 0, stream,
                       x, W, b, nullptr, nullptr, nullptr, out);
  }
}